// Round 6
// baseline (341.824 us; speedup 1.0000x reference)
//
#include <hip/hip_runtime.h>
#include <cstdint>
#include <cstddef>

#define IN_F 4096
#define OUT_F 4096

typedef __attribute__((ext_vector_type(8))) short bf16x8;
typedef __attribute__((ext_vector_type(4))) float f32x4;

__device__ __forceinline__ ushort f32_bf16_rne(float f) {
    uint32_t u = __builtin_bit_cast(uint32_t, f);
    uint32_t r = (u + 0x7FFFu + ((u >> 16) & 1u)) >> 16;
    return (ushort)r;
}

__device__ __forceinline__ void gload_lds16(const void* g, void* l) {
    __builtin_amdgcn_global_load_lds(
        (const __attribute__((address_space(1))) uint32_t*)g,
        (__attribute__((address_space(3))) uint32_t*)l,
        16, 0, 0);
}

// Light barrier: memory clobber orders LDS/global ops across it without
// sched_barrier(0) pinning (m141).
__device__ __forceinline__ void bar() {
    asm volatile("s_barrier" ::: "memory");
}

// ---------- deterministic |W| reduction (fixed order, no atomics) ----------
__global__ void reduce_abs1(const float* __restrict__ W, float* __restrict__ part) {
    __shared__ float sm[256];
    const int b = blockIdx.x, t = threadIdx.x;
    const float* p = W + (size_t)b * 4096;
    float s = 0.f;
#pragma unroll
    for (int j = 0; j < 16; ++j) s += fabsf(p[t + 256 * j]);
    sm[t] = s;
    __syncthreads();
    for (int w = 128; w > 0; w >>= 1) {
        if (t < w) sm[t] += sm[t + w];
        __syncthreads();
    }
    if (t == 0) part[b] = sm[0];
}

__global__ void reduce_abs2(const float* __restrict__ part, float* __restrict__ scale) {
    __shared__ float sm[256];
    const int t = threadIdx.x;
    float s = 0.f;
#pragma unroll
    for (int j = 0; j < 16; ++j) s += part[t + 256 * j];
    sm[t] = s;
    __syncthreads();
    for (int w = 128; w > 0; w >>= 1) {
        if (t < w) sm[t] += sm[t + w];
        __syncthreads();
    }
    if (t == 0) {
        float m = sm[0] / 16777216.0f;
        *scale = fmaxf(m, 1e-8f);
    }
}

// ---------- quantize W -> bf16 {-2,-1,0,1,2} (exact in bf16) ----------
__global__ void quantize_w(const float* __restrict__ W, ushort* __restrict__ wq,
                           const float* __restrict__ scale_p) {
    const int i = blockIdx.x * 256 + threadIdx.x;
    const float s = *scale_p;
    float4 v = ((const float4*)W)[i];
    float q0 = fminf(fmaxf(rintf(v.x / s), -2.f), 2.f);
    float q1 = fminf(fmaxf(rintf(v.y / s), -2.f), 2.f);
    float q2 = fminf(fmaxf(rintf(v.z / s), -2.f), 2.f);
    float q3 = fminf(fmaxf(rintf(v.w / s), -2.f), 2.f);
    ushort4 o;
    o.x = f32_bf16_rne(q0); o.y = f32_bf16_rne(q1);
    o.z = f32_bf16_rne(q2); o.w = f32_bf16_rne(q3);
    ((ushort4*)wq)[i] = o;
}

// ---------- cast x -> bf16 (RNE) ----------
__global__ void cast_x(const float* __restrict__ X, ushort* __restrict__ xh) {
    const int i = blockIdx.x * 256 + threadIdx.x;
    float4 v = ((const float4*)X)[i];
    ushort4 o;
    o.x = f32_bf16_rne(v.x); o.y = f32_bf16_rne(v.y);
    o.z = f32_bf16_rne(v.z); o.w = f32_bf16_rne(v.w);
    ((ushort4*)xh)[i] = o;
}

// ============== 256x256 pipelined GEMM (read-ahead interleave) ==============
// C = scale * (A @ B^T).  A:[M][K] bf16, B:[N][K] bf16 (both K-contiguous).
// 512 threads = 8 waves (2M x 4N); per-wave output 128x64 (acc[8][4]).
// LDS 128 KiB: 2 K-tile buffers x {A0,A1,B0,B1} 16 KiB half-tiles (128x64),
// XOR-swizzled (byte ^= (r&7)<<4), pre-swizzled global source (rule #21).
//
// ds_reads are issued one quadrant AHEAD, inside the barrier region next to
// a register-independent MFMA cluster, so the LDS pipe drains under the MFMA
// pipe instead of serializing with it:
//   P1: stage; bar; {read a1      | MFMA Q00(a0 x b01)}; bar
//   P2: stage; bar; {read b23     | MFMA Q10(a1 x b01)}; bar
//   P3: stage; bar; {             | MFMA Q01(a0 x b23)}; bar
//   P4: vmcnt; stage; bar; {read next a0,b01 | MFMA Q11(a1 x b23)}; bar
// Steady state: vmcnt(4) at P4 leaves only tile-(kt+2) A0/A1 in flight; tile
// kt+1 is fully landed before its read-ahead.
// TAIL (R5 bug -> fixed): at kt==NT-2 the skipped stages stop pushing the
// counter, so the 4 outstanding instrs ARE the last tile's B0/B1 -> must
// drain with vmcnt(0) before the read-ahead of the final tile.
#define BK 64
#define HT_BYTES 16384
#define BUF_BYTES 65536

__global__ __launch_bounds__(512, 2) void qgemm256(
        const ushort* __restrict__ Ab, const ushort* __restrict__ Bq,
        float* __restrict__ C, const float* __restrict__ scale_p,
        int M, int N, int K) {
    extern __shared__ __align__(16) char smem[];

    const int t = threadIdx.x;
    const int lane = t & 63;
    const int w = t >> 6;
    const int wr = w >> 2;   // 0..1 (M half)
    const int wc = w & 3;    // 0..3 (N quarter)
    const int bh = wc >> 1;  // B half

    // XCD-bijective block swizzle (grid = 512, 512 % 8 == 0)
    const int nwg = gridDim.x;
    int wg = blockIdx.x;
    if ((nwg & 7) == 0) wg = (wg & 7) * (nwg >> 3) + (wg >> 3);
    const int MT = M >> 8;
    const int m0 = (wg % MT) << 8;
    const int n0 = (wg / MT) << 8;

    const int NT = K / BK;    // K-tiles
    const int NS = NT * 4;    // half-tile stream length

    // per-lane ds_read byte offsets within a half-tile (add frag*2048 above)
    int pre[2];
#pragma unroll
    for (int ks = 0; ks < 2; ++ks)
        pre[ks] = (lane & 15) * 128 +
                  (((ks * 64) + ((lane >> 4) * 16)) ^ ((lane & 7) << 4));

    // stream s: kt = s>>2, h = s&3; h: 0->A0, 1->A1, 2->B0, 3->B1
    auto do_stage = [&](int s) {
        if (s >= NS) return;
        const int kt = s >> 2, h = s & 3;
        const int k0 = kt * BK;
        char* bufbase = smem + (kt & 1) * BUF_BYTES;
        char* region;
        const ushort* gsrc;
        if (h < 2) {
            region = bufbase + h * HT_BYTES;
            gsrc = Ab + (size_t)(m0 + h * 128) * K + k0;
        } else {
            region = bufbase + 32768 + (h - 2) * HT_BYTES;
            gsrc = Bq + (size_t)(n0 + (h - 2) * 128) * K + k0;
        }
#pragma unroll
        for (int j = 0; j < 2; ++j) {
            int e = j * 4096 + t * 8;          // element in 128x64 half-tile
            int r = e >> 6, c8 = (e >> 3) & 7;
            int srcc = (c8 ^ (r & 7)) * 8;     // pre-swizzled global column
            gload_lds16(gsrc + (size_t)r * K + srcc, region + e * 2);
        }
    };

    f32x4 acc[8][4];
#pragma unroll
    for (int m = 0; m < 8; ++m)
#pragma unroll
        for (int n = 0; n < 4; ++n) acc[m][n] = (f32x4){0.f, 0.f, 0.f, 0.f};

    bf16x8 a0[4][2], a1[4][2], b01[2][2], b23[2][2];

    // ---- prologue: stage tile 0 + 3 halves of tile 1; preload Q00 regs ----
    do_stage(0); do_stage(1); do_stage(2); do_stage(3);
    do_stage(4); do_stage(5); do_stage(6);
    asm volatile("s_waitcnt vmcnt(6)" ::: "memory");  // own tile-0 loads done
    bar();                                            // -> tile 0 visible
    {
        const char* aB = smem + wr * HT_BYTES;
        const char* bB = smem + 32768 + bh * HT_BYTES + (wc & 1) * 8192;
#pragma unroll
        for (int m = 0; m < 4; ++m)
#pragma unroll
            for (int ks = 0; ks < 2; ++ks)
                a0[m][ks] = *(const bf16x8*)(aB + m * 2048 + pre[ks]);
#pragma unroll
        for (int n = 0; n < 2; ++n)
#pragma unroll
            for (int ks = 0; ks < 2; ++ks)
                b01[n][ks] = *(const bf16x8*)(bB + n * 2048 + pre[ks]);
    }

    for (int kt = 0; kt < NT; ++kt) {
        const char* aB = smem + (kt & 1) * BUF_BYTES + wr * HT_BYTES;
        const char* bB = smem + (kt & 1) * BUF_BYTES + 32768 + bh * HT_BYTES +
                         (wc & 1) * 8192;
        const char* aBn = smem + ((kt + 1) & 1) * BUF_BYTES + wr * HT_BYTES;
        const char* bBn = smem + ((kt + 1) & 1) * BUF_BYTES + 32768 +
                          bh * HT_BYTES + (wc & 1) * 8192;

        // -------- P1: {read a1 | MFMA Q00} --------
        do_stage(7 + 4 * kt);
        bar();
        __builtin_amdgcn_s_setprio(1);
#pragma unroll
        for (int m = 0; m < 4; ++m)
#pragma unroll
            for (int ks = 0; ks < 2; ++ks)
                a1[m][ks] = *(const bf16x8*)(aB + (m + 4) * 2048 + pre[ks]);
#pragma unroll
        for (int m = 0; m < 4; ++m)
#pragma unroll
            for (int n = 0; n < 2; ++n)
#pragma unroll
                for (int ks = 0; ks < 2; ++ks)
                    acc[m][n] = __builtin_amdgcn_mfma_f32_16x16x32_bf16(
                        a0[m][ks], b01[n][ks], acc[m][n], 0, 0, 0);
        __builtin_amdgcn_s_setprio(0);
        bar();

        // -------- P2: {read b23 | MFMA Q10} --------
        do_stage(8 + 4 * kt);
        bar();
        __builtin_amdgcn_s_setprio(1);
#pragma unroll
        for (int n = 0; n < 2; ++n)
#pragma unroll
            for (int ks = 0; ks < 2; ++ks)
                b23[n][ks] = *(const bf16x8*)(bB + (n + 2) * 2048 + pre[ks]);
#pragma unroll
        for (int m = 0; m < 4; ++m)
#pragma unroll
            for (int n = 0; n < 2; ++n)
#pragma unroll
                for (int ks = 0; ks < 2; ++ks)
                    acc[m + 4][n] = __builtin_amdgcn_mfma_f32_16x16x32_bf16(
                        a1[m][ks], b01[n][ks], acc[m + 4][n], 0, 0, 0);
        __builtin_amdgcn_s_setprio(0);
        bar();

        // -------- P3: {MFMA Q01} --------
        do_stage(9 + 4 * kt);
        bar();
        __builtin_amdgcn_s_setprio(1);
#pragma unroll
        for (int m = 0; m < 4; ++m)
#pragma unroll
            for (int n = 0; n < 2; ++n)
#pragma unroll
                for (int ks = 0; ks < 2; ++ks)
                    acc[m][n + 2] = __builtin_amdgcn_mfma_f32_16x16x32_bf16(
                        a0[m][ks], b23[n][ks], acc[m][n + 2], 0, 0, 0);
        __builtin_amdgcn_s_setprio(0);
        bar();

        // -------- P4: {read next a0,b01 | MFMA Q11} --------
        // Steady state (kt < NT-2): issued stages reach s=9+4kt; vmcnt(4)
        // leaves only tile-(kt+2) A0/A1 (4 instr) outstanding -> tile kt+1
        // fully landed.  TAIL (kt >= NT-2): skipped stages no longer push
        // the count, so the 4 newest instrs ARE the last tile's B0/B1 ->
        // full drain required before the read-ahead (R5 race, fixed).
        if (kt < NT - 2) {
            asm volatile("s_waitcnt vmcnt(4)" ::: "memory");
        } else {
            asm volatile("s_waitcnt vmcnt(0)" ::: "memory");
        }
        do_stage(10 + 4 * kt);
        bar();  // all waves passed the waitcnt -> tile kt+1 visible
        __builtin_amdgcn_s_setprio(1);
        if (kt + 1 < NT) {
#pragma unroll
            for (int m = 0; m < 4; ++m)
#pragma unroll
                for (int ks = 0; ks < 2; ++ks)
                    a0[m][ks] = *(const bf16x8*)(aBn + m * 2048 + pre[ks]);
#pragma unroll
            for (int n = 0; n < 2; ++n)
#pragma unroll
                for (int ks = 0; ks < 2; ++ks)
                    b01[n][ks] = *(const bf16x8*)(bBn + n * 2048 + pre[ks]);
        }
#pragma unroll
        for (int m = 0; m < 4; ++m)
#pragma unroll
            for (int n = 0; n < 2; ++n)
#pragma unroll
                for (int ks = 0; ks < 2; ++ks)
                    acc[m + 4][n + 2] = __builtin_amdgcn_mfma_f32_16x16x32_bf16(
                        a1[m][ks], b23[n][ks], acc[m + 4][n + 2], 0, 0, 0);
        __builtin_amdgcn_s_setprio(0);
        bar();
    }

    const float s = *scale_p;
#pragma unroll
    for (int m = 0; m < 8; ++m)
#pragma unroll
        for (int n = 0; n < 4; ++n) {
            const int col = n0 + wc * 64 + n * 16 + (lane & 15);
            const int rbase = m0 + wr * 128 + m * 16 + ((lane >> 4) << 2);
#pragma unroll
            for (int j = 0; j < 4; ++j)
                C[(size_t)(rbase + j) * N + col] = s * acc[m][n][j];
        }
}

// ---------- 128^2 fallback (validated round 2) ----------
template <bool ABF16>
__global__ __launch_bounds__(256) void qgemm(const void* __restrict__ Aptr,
                                             const ushort* __restrict__ Bq,
                                             float* __restrict__ C,
                                             const float* __restrict__ scale_p,
                                             int M, int N, int K) {
    __shared__ __align__(16) ushort sA[128 * 64];
    __shared__ __align__(16) ushort sB[128 * 64];

    const int t = threadIdx.x;
    const int lane = t & 63;
    const int w = t >> 6;
    const int wr = w >> 1, wc = w & 1;

    const int nwg = gridDim.x;
    int wg = blockIdx.x;
    if ((nwg & 7) == 0) wg = (wg & 7) * (nwg >> 3) + (wg >> 3);
    const int MT = M >> 7;
    const int mt = wg % MT;
    const int nt = wg / MT;
    const int m0 = mt * 128, n0 = nt * 128;

    const ushort* Ab = (const ushort*)Aptr;
    const float* Af = (const float*)Aptr;

    f32x4 zero = {0.f, 0.f, 0.f, 0.f};
    f32x4 acc[4][4];
#pragma unroll
    for (int m = 0; m < 4; ++m)
#pragma unroll
        for (int n = 0; n < 4; ++n) acc[m][n] = zero;

    for (int k0 = 0; k0 < K; k0 += 64) {
#pragma unroll
        for (int i = 0; i < 4; ++i) {
            int e = i * 2048 + t * 8;
            int r = e >> 6, c8 = (e >> 3) & 7;
            int srcc = (c8 ^ (r & 7)) * 8;
            gload_lds16(Bq + (size_t)(n0 + r) * K + (k0 + srcc), &sB[e]);
        }
        if constexpr (ABF16) {
#pragma unroll
            for (int i = 0; i < 4; ++i) {
                int e = i * 2048 + t * 8;
                int r = e >> 6, c8 = (e >> 3) & 7;
                int srcc = (c8 ^ (r & 7)) * 8;
                gload_lds16(Ab + (size_t)(m0 + r) * K + (k0 + srcc), &sA[e]);
            }
        } else {
#pragma unroll
            for (int i = 0; i < 4; ++i) {
                int e = i * 2048 + t * 8;
                int r = e >> 6, c = e & 63;
                const float* src = Af + (size_t)(m0 + r) * K + (k0 + c);
                float4 v0 = *(const float4*)src;
                float4 v1 = *(const float4*)(src + 4);
                bf16x8 pk;
                pk[0] = (short)f32_bf16_rne(v0.x); pk[1] = (short)f32_bf16_rne(v0.y);
                pk[2] = (short)f32_bf16_rne(v0.z); pk[3] = (short)f32_bf16_rne(v0.w);
                pk[4] = (short)f32_bf16_rne(v1.x); pk[5] = (short)f32_bf16_rne(v1.y);
                pk[6] = (short)f32_bf16_rne(v1.z); pk[7] = (short)f32_bf16_rne(v1.w);
                int byte = (r * 128 + c * 2) ^ ((r & 7) << 4);
                *(bf16x8*)((char*)sA + byte) = pk;
            }
        }
        __syncthreads();

#pragma unroll
        for (int ks = 0; ks < 2; ++ks) {
            const int kk = ks * 32 + ((lane >> 4) << 3);
            bf16x8 afr[4], bfr[4];
#pragma unroll
            for (int m = 0; m < 4; ++m) {
                int r = wr * 64 + m * 16 + (lane & 15);
                int byte = (r * 128 + kk * 2) ^ ((r & 7) << 4);
                afr[m] = *(const bf16x8*)((const char*)sA + byte);
            }
#pragma unroll
            for (int n = 0; n < 4; ++n) {
                int r = wc * 64 + n * 16 + (lane & 15);
                int byte = (r * 128 + kk * 2) ^ ((r & 7) << 4);
                bfr[n] = *(const bf16x8*)((const char*)sB + byte);
            }
#pragma unroll
            for (int m = 0; m < 4; ++m)
#pragma unroll
                for (int n = 0; n < 4; ++n)
                    acc[m][n] = __builtin_amdgcn_mfma_f32_16x16x32_bf16(
                        afr[m], bfr[n], acc[m][n], 0, 0, 0);
        }
        __syncthreads();
    }

    const float s = *scale_p;
#pragma unroll
    for (int m = 0; m < 4; ++m)
#pragma unroll
        for (int n = 0; n < 4; ++n) {
            const int col = n0 + wc * 64 + n * 16 + (lane & 15);
            const int rbase = m0 + wr * 64 + m * 16 + ((lane >> 4) << 2);
#pragma unroll
            for (int j = 0; j < 4; ++j)
                C[(size_t)(rbase + j) * N + col] = s * acc[m][n][j];
        }
}

// ---------- last-resort naive path ----------
__global__ void naive_qgemm(const float* __restrict__ X, const float* __restrict__ W,
                            float* __restrict__ out, const float* __restrict__ scale_p,
                            int M) {
    const int col = blockIdx.x * 256 + threadIdx.x;
    const int row = blockIdx.y;
    const float s = *scale_p;
    const float inv = 1.0f / s;
    const float* xr = X + (size_t)row * IN_F;
    const float* wrow = W + (size_t)col * IN_F;
    float acc = 0.f;
    for (int k = 0; k < IN_F; ++k) {
        float q = fminf(fmaxf(rintf(wrow[k] * inv), -2.f), 2.f);
        acc += xr[k] * q;
    }
    out[(size_t)row * OUT_F + col] = acc * s;
}

extern "C" void kernel_launch(void* const* d_in, const int* in_sizes, int n_in,
                              void* d_out, int out_size, void* d_ws, size_t ws_size,
                              hipStream_t stream) {
    const float* x = (const float*)d_in[0];
    const float* W = (const float*)d_in[1];
    float* out = (float*)d_out;
    const int M = in_sizes[0] / IN_F;  // 8192
    const int K = IN_F, N = OUT_F;

    char* ws = (char*)d_ws;
    const size_t OFF_PART = 512;
    const size_t OFF_WQ = OFF_PART + 4096 * sizeof(float);
    const size_t WQ_BYTES = (size_t)N * K * sizeof(ushort);
    const size_t OFF_XH = OFF_WQ + WQ_BYTES;
    const size_t XH_BYTES = (size_t)M * K * sizeof(ushort);
    float* scale = (float*)(ws + 0);
    float* part = (float*)(ws + OFF_PART);
    ushort* wq = (ushort*)(ws + OFF_WQ);
    ushort* xh = (ushort*)(ws + OFF_XH);

    if (ws_size < OFF_WQ) return;

    reduce_abs1<<<4096, 256, 0, stream>>>(W, part);
    reduce_abs2<<<1, 256, 0, stream>>>(part, scale);

    if (ws_size >= OFF_XH + XH_BYTES && (M % 256) == 0 && (N % 256) == 0) {
        quantize_w<<<(N * K / 4) / 256, 256, 0, stream>>>(W, wq, scale);
        cast_x<<<(M * K / 4) / 256, 256, 0, stream>>>(x, xh);
        (void)hipFuncSetAttribute((const void*)qgemm256,
                                  hipFuncAttributeMaxDynamicSharedMemorySize,
                                  131072);
        qgemm256<<<(M / 256) * (N / 256), 512, 131072, stream>>>(
            xh, wq, out, scale, M, N, K);
    } else if (ws_size >= OFF_XH + XH_BYTES) {
        quantize_w<<<(N * K / 4) / 256, 256, 0, stream>>>(W, wq, scale);
        cast_x<<<(M * K / 4) / 256, 256, 0, stream>>>(x, xh);
        qgemm<true><<<(M / 128) * (N / 128), 256, 0, stream>>>(xh, wq, out, scale, M, N, K);
    } else if (ws_size >= OFF_WQ + WQ_BYTES) {
        quantize_w<<<(N * K / 4) / 256, 256, 0, stream>>>(W, wq, scale);
        qgemm<false><<<(M / 128) * (N / 128), 256, 0, stream>>>(x, wq, out, scale, M, N, K);
    } else {
        naive_qgemm<<<dim3(N / 256, M), 256, 0, stream>>>(x, W, out, scale, M);
    }
}

// Round 7
// 328.641 us; speedup vs baseline: 1.0401x; 1.0401x over previous
//
#include <hip/hip_runtime.h>
#include <cstdint>
#include <cstddef>

#define IN_F 4096
#define OUT_F 4096

typedef __attribute__((ext_vector_type(8))) short bf16x8;
typedef __attribute__((ext_vector_type(4))) float f32x4;

__device__ __forceinline__ ushort f32_bf16_rne(float f) {
    uint32_t u = __builtin_bit_cast(uint32_t, f);
    uint32_t r = (u + 0x7FFFu + ((u >> 16) & 1u)) >> 16;
    return (ushort)r;
}

__device__ __forceinline__ void gload_lds16(const void* g, void* l) {
    __builtin_amdgcn_global_load_lds(
        (const __attribute__((address_space(1))) uint32_t*)g,
        (__attribute__((address_space(3))) uint32_t*)l,
        16, 0, 0);
}

// Light barrier: memory clobber orders LDS/global ops across it without
// sched_barrier(0) pinning (m141).
__device__ __forceinline__ void bar() {
    asm volatile("s_barrier" ::: "memory");
}

// ---------- deterministic |W| reduction (fixed order, no atomics) ----------
__global__ void reduce_abs1(const float* __restrict__ W, float* __restrict__ part) {
    __shared__ float sm[256];
    const int b = blockIdx.x, t = threadIdx.x;
    const float* p = W + (size_t)b * 4096;
    float s = 0.f;
#pragma unroll
    for (int j = 0; j < 16; ++j) s += fabsf(p[t + 256 * j]);
    sm[t] = s;
    __syncthreads();
    for (int w = 128; w > 0; w >>= 1) {
        if (t < w) sm[t] += sm[t + w];
        __syncthreads();
    }
    if (t == 0) part[b] = sm[0];
}

__global__ void reduce_abs2(const float* __restrict__ part, float* __restrict__ scale) {
    __shared__ float sm[256];
    const int t = threadIdx.x;
    float s = 0.f;
#pragma unroll
    for (int j = 0; j < 16; ++j) s += part[t + 256 * j];
    sm[t] = s;
    __syncthreads();
    for (int w = 128; w > 0; w >>= 1) {
        if (t < w) sm[t] += sm[t + w];
        __syncthreads();
    }
    if (t == 0) {
        float m = sm[0] / 16777216.0f;
        *scale = fmaxf(m, 1e-8f);
    }
}

// ---------- quantize W -> bf16 {-2,-1,0,1,2} (exact in bf16) ----------
__global__ void quantize_w(const float* __restrict__ W, ushort* __restrict__ wq,
                           const float* __restrict__ scale_p) {
    const int i = blockIdx.x * 256 + threadIdx.x;
    const float s = *scale_p;
    float4 v = ((const float4*)W)[i];
    float q0 = fminf(fmaxf(rintf(v.x / s), -2.f), 2.f);
    float q1 = fminf(fmaxf(rintf(v.y / s), -2.f), 2.f);
    float q2 = fminf(fmaxf(rintf(v.z / s), -2.f), 2.f);
    float q3 = fminf(fmaxf(rintf(v.w / s), -2.f), 2.f);
    ushort4 o;
    o.x = f32_bf16_rne(q0); o.y = f32_bf16_rne(q1);
    o.z = f32_bf16_rne(q2); o.w = f32_bf16_rne(q3);
    ((ushort4*)wq)[i] = o;
}

// ---------- cast x -> bf16 (RNE) ----------
__global__ void cast_x(const float* __restrict__ X, ushort* __restrict__ xh) {
    const int i = blockIdx.x * 256 + threadIdx.x;
    float4 v = ((const float4*)X)[i];
    ushort4 o;
    o.x = f32_bf16_rne(v.x); o.y = f32_bf16_rne(v.y);
    o.z = f32_bf16_rne(v.z); o.w = f32_bf16_rne(v.w);
    ((ushort4*)xh)[i] = o;
}

// ============== 256x256 pipelined GEMM (R6 schedule + 2D XCD supertiling) ==============
// C = scale * (A @ B^T).  A:[M][K] bf16, B:[N][K] bf16 (both K-contiguous).
// 512 threads = 8 waves (2M x 4N); per-wave output 128x64 (acc[8][4]).
// LDS 128 KiB: 2 K-tile buffers x {A0,A1,B0,B1} 16 KiB half-tiles (128x64),
// XOR-swizzled (byte ^= (r&7)<<4), pre-swizzled global source (rule #21).
//
// R7 change (ONLY): wg -> (mt,nt) mapping. R1-R6's M-major XCD swizzle gave
// each XCD a full M-column strip -> every XCD streamed ALL of A per round
// (FETCH_SIZE 541MB = 8 x 67MB; fabric-BW-bound at 2.4 TB/s; all schedule
// tweaks neutral). Now: XCDs tiled 4x2, each XCD's 32 concurrent blocks form
// an 8mt x 4nt SQUARE patch (disjoint A-rows/B-cols across XCDs, two
// N-rounds). Per-K-slab L2 working set/XCD ~384KB << 4MB -> A,B fetched
// ~once; re-reads L2/L3-hit.
#define BK 64
#define HT_BYTES 16384
#define BUF_BYTES 65536

__global__ __launch_bounds__(512, 2) void qgemm256(
        const ushort* __restrict__ Ab, const ushort* __restrict__ Bq,
        float* __restrict__ C, const float* __restrict__ scale_p,
        int M, int N, int K) {
    extern __shared__ __align__(16) char smem[];

    const int t = threadIdx.x;
    const int lane = t & 63;
    const int w = t >> 6;
    const int wr = w >> 2;   // 0..1 (M half)
    const int wc = w & 3;    // 0..3 (N quarter)
    const int bh = wc >> 1;  // B half

    // ---- 2D XCD-aware supertiling (bijective; HW round-robins b%8 -> XCD) ----
    const int MT = M >> 8;
    const int NTiles = N >> 8;
    int mt, nt;
    if (MT == 32 && NTiles == 16 && gridDim.x == 512) {
        const int x = blockIdx.x & 7;        // XCD id (dispatch round-robin)
        const int j = blockIdx.x >> 3;       // per-XCD sequence 0..63
        const int jr = j & 31;               // within dispatch round
        const int r = j >> 5;                // N-round 0..1
        mt = (x & 3) * 8 + (jr & 7);         // XCD-row (4) x 8 tiles
        nt = r * 8 + (x >> 2) * 4 + (jr >> 3);  // XCD-col (2) x 4 tiles
    } else {
        const int nwg = gridDim.x;
        int wg = blockIdx.x;
        if ((nwg & 7) == 0) wg = (wg & 7) * (nwg >> 3) + (wg >> 3);
        mt = wg % MT; nt = wg / MT;
    }
    const int m0 = mt << 8;
    const int n0 = nt << 8;

    const int NT = K / BK;    // K-tiles
    const int NS = NT * 4;    // half-tile stream length

    // per-lane ds_read byte offsets within a half-tile (add frag*2048 above)
    int pre[2];
#pragma unroll
    for (int ks = 0; ks < 2; ++ks)
        pre[ks] = (lane & 15) * 128 +
                  (((ks * 64) + ((lane >> 4) * 16)) ^ ((lane & 7) << 4));

    // stream s: kt = s>>2, h = s&3; h: 0->A0, 1->A1, 2->B0, 3->B1
    auto do_stage = [&](int s) {
        if (s >= NS) return;
        const int kt = s >> 2, h = s & 3;
        const int k0 = kt * BK;
        char* bufbase = smem + (kt & 1) * BUF_BYTES;
        char* region;
        const ushort* gsrc;
        if (h < 2) {
            region = bufbase + h * HT_BYTES;
            gsrc = Ab + (size_t)(m0 + h * 128) * K + k0;
        } else {
            region = bufbase + 32768 + (h - 2) * HT_BYTES;
            gsrc = Bq + (size_t)(n0 + (h - 2) * 128) * K + k0;
        }
#pragma unroll
        for (int j = 0; j < 2; ++j) {
            int e = j * 4096 + t * 8;          // element in 128x64 half-tile
            int r = e >> 6, c8 = (e >> 3) & 7;
            int srcc = (c8 ^ (r & 7)) * 8;     // pre-swizzled global column
            gload_lds16(gsrc + (size_t)r * K + srcc, region + e * 2);
        }
    };

    f32x4 acc[8][4];
#pragma unroll
    for (int m = 0; m < 8; ++m)
#pragma unroll
        for (int n = 0; n < 4; ++n) acc[m][n] = (f32x4){0.f, 0.f, 0.f, 0.f};

    bf16x8 a0[4][2], a1[4][2], b01[2][2], b23[2][2];

    // ---- prologue: stage tile 0 + 3 halves of tile 1; preload Q00 regs ----
    do_stage(0); do_stage(1); do_stage(2); do_stage(3);
    do_stage(4); do_stage(5); do_stage(6);
    asm volatile("s_waitcnt vmcnt(6)" ::: "memory");  // own tile-0 loads done
    bar();                                            // -> tile 0 visible
    {
        const char* aB = smem + wr * HT_BYTES;
        const char* bB = smem + 32768 + bh * HT_BYTES + (wc & 1) * 8192;
#pragma unroll
        for (int m = 0; m < 4; ++m)
#pragma unroll
            for (int ks = 0; ks < 2; ++ks)
                a0[m][ks] = *(const bf16x8*)(aB + m * 2048 + pre[ks]);
#pragma unroll
        for (int n = 0; n < 2; ++n)
#pragma unroll
            for (int ks = 0; ks < 2; ++ks)
                b01[n][ks] = *(const bf16x8*)(bB + n * 2048 + pre[ks]);
    }

    for (int kt = 0; kt < NT; ++kt) {
        const char* aB = smem + (kt & 1) * BUF_BYTES + wr * HT_BYTES;
        const char* bB = smem + (kt & 1) * BUF_BYTES + 32768 + bh * HT_BYTES +
                         (wc & 1) * 8192;
        const char* aBn = smem + ((kt + 1) & 1) * BUF_BYTES + wr * HT_BYTES;
        const char* bBn = smem + ((kt + 1) & 1) * BUF_BYTES + 32768 +
                          bh * HT_BYTES + (wc & 1) * 8192;

        // -------- P1: {read a1 | MFMA Q00} --------
        do_stage(7 + 4 * kt);
        bar();
        __builtin_amdgcn_s_setprio(1);
#pragma unroll
        for (int m = 0; m < 4; ++m)
#pragma unroll
            for (int ks = 0; ks < 2; ++ks)
                a1[m][ks] = *(const bf16x8*)(aB + (m + 4) * 2048 + pre[ks]);
#pragma unroll
        for (int m = 0; m < 4; ++m)
#pragma unroll
            for (int n = 0; n < 2; ++n)
#pragma unroll
                for (int ks = 0; ks < 2; ++ks)
                    acc[m][n] = __builtin_amdgcn_mfma_f32_16x16x32_bf16(
                        a0[m][ks], b01[n][ks], acc[m][n], 0, 0, 0);
        __builtin_amdgcn_s_setprio(0);
        bar();

        // -------- P2: {read b23 | MFMA Q10} --------
        do_stage(8 + 4 * kt);
        bar();
        __builtin_amdgcn_s_setprio(1);
#pragma unroll
        for (int n = 0; n < 2; ++n)
#pragma unroll
            for (int ks = 0; ks < 2; ++ks)
                b23[n][ks] = *(const bf16x8*)(bB + (n + 2) * 2048 + pre[ks]);
#pragma unroll
        for (int m = 0; m < 4; ++m)
#pragma unroll
            for (int n = 0; n < 2; ++n)
#pragma unroll
                for (int ks = 0; ks < 2; ++ks)
                    acc[m + 4][n] = __builtin_amdgcn_mfma_f32_16x16x32_bf16(
                        a1[m][ks], b01[n][ks], acc[m + 4][n], 0, 0, 0);
        __builtin_amdgcn_s_setprio(0);
        bar();

        // -------- P3: {MFMA Q01} --------
        do_stage(9 + 4 * kt);
        bar();
        __builtin_amdgcn_s_setprio(1);
#pragma unroll
        for (int m = 0; m < 4; ++m)
#pragma unroll
            for (int n = 0; n < 2; ++n)
#pragma unroll
                for (int ks = 0; ks < 2; ++ks)
                    acc[m][n + 2] = __builtin_amdgcn_mfma_f32_16x16x32_bf16(
                        a0[m][ks], b23[n][ks], acc[m][n + 2], 0, 0, 0);
        __builtin_amdgcn_s_setprio(0);
        bar();

        // -------- P4: {read next a0,b01 | MFMA Q11} --------
        // Steady state (kt < NT-2): vmcnt(4) leaves only tile-(kt+2) A0/A1
        // outstanding -> tile kt+1 fully landed.  TAIL (kt >= NT-2): skipped
        // stages stop pushing the count -> full drain (R5 race fix).
        if (kt < NT - 2) {
            asm volatile("s_waitcnt vmcnt(4)" ::: "memory");
        } else {
            asm volatile("s_waitcnt vmcnt(0)" ::: "memory");
        }
        do_stage(10 + 4 * kt);
        bar();  // all waves passed the waitcnt -> tile kt+1 visible
        __builtin_amdgcn_s_setprio(1);
        if (kt + 1 < NT) {
#pragma unroll
            for (int m = 0; m < 4; ++m)
#pragma unroll
                for (int ks = 0; ks < 2; ++ks)
                    a0[m][ks] = *(const bf16x8*)(aBn + m * 2048 + pre[ks]);
#pragma unroll
            for (int n = 0; n < 2; ++n)
#pragma unroll
                for (int ks = 0; ks < 2; ++ks)
                    b01[n][ks] = *(const bf16x8*)(bBn + n * 2048 + pre[ks]);
        }
#pragma unroll
        for (int m = 0; m < 4; ++m)
#pragma unroll
            for (int n = 0; n < 2; ++n)
#pragma unroll
                for (int ks = 0; ks < 2; ++ks)
                    acc[m + 4][n + 2] = __builtin_amdgcn_mfma_f32_16x16x32_bf16(
                        a1[m][ks], b23[n][ks], acc[m + 4][n + 2], 0, 0, 0);
        __builtin_amdgcn_s_setprio(0);
        bar();
    }

    const float s = *scale_p;
#pragma unroll
    for (int m = 0; m < 8; ++m)
#pragma unroll
        for (int n = 0; n < 4; ++n) {
            const int col = n0 + wc * 64 + n * 16 + (lane & 15);
            const int rbase = m0 + wr * 128 + m * 16 + ((lane >> 4) << 2);
#pragma unroll
            for (int j = 0; j < 4; ++j)
                C[(size_t)(rbase + j) * N + col] = s * acc[m][n][j];
        }
}

// ---------- 128^2 fallback (validated round 2) ----------
template <bool ABF16>
__global__ __launch_bounds__(256) void qgemm(const void* __restrict__ Aptr,
                                             const ushort* __restrict__ Bq,
                                             float* __restrict__ C,
                                             const float* __restrict__ scale_p,
                                             int M, int N, int K) {
    __shared__ __align__(16) ushort sA[128 * 64];
    __shared__ __align__(16) ushort sB[128 * 64];

    const int t = threadIdx.x;
    const int lane = t & 63;
    const int w = t >> 6;
    const int wr = w >> 1, wc = w & 1;

    const int nwg = gridDim.x;
    int wg = blockIdx.x;
    if ((nwg & 7) == 0) wg = (wg & 7) * (nwg >> 3) + (wg >> 3);
    const int MT = M >> 7;
    const int mt = wg % MT;
    const int nt = wg / MT;
    const int m0 = mt * 128, n0 = nt * 128;

    const ushort* Ab = (const ushort*)Aptr;
    const float* Af = (const float*)Aptr;

    f32x4 zero = {0.f, 0.f, 0.f, 0.f};
    f32x4 acc[4][4];
#pragma unroll
    for (int m = 0; m < 4; ++m)
#pragma unroll
        for (int n = 0; n < 4; ++n) acc[m][n] = zero;

    for (int k0 = 0; k0 < K; k0 += 64) {
#pragma unroll
        for (int i = 0; i < 4; ++i) {
            int e = i * 2048 + t * 8;
            int r = e >> 6, c8 = (e >> 3) & 7;
            int srcc = (c8 ^ (r & 7)) * 8;
            gload_lds16(Bq + (size_t)(n0 + r) * K + (k0 + srcc), &sB[e]);
        }
        if constexpr (ABF16) {
#pragma unroll
            for (int i = 0; i < 4; ++i) {
                int e = i * 2048 + t * 8;
                int r = e >> 6, c8 = (e >> 3) & 7;
                int srcc = (c8 ^ (r & 7)) * 8;
                gload_lds16(Ab + (size_t)(m0 + r) * K + (k0 + srcc), &sA[e]);
            }
        } else {
#pragma unroll
            for (int i = 0; i < 4; ++i) {
                int e = i * 2048 + t * 8;
                int r = e >> 6, c = e & 63;
                const float* src = Af + (size_t)(m0 + r) * K + (k0 + c);
                float4 v0 = *(const float4*)src;
                float4 v1 = *(const float4*)(src + 4);
                bf16x8 pk;
                pk[0] = (short)f32_bf16_rne(v0.x); pk[1] = (short)f32_bf16_rne(v0.y);
                pk[2] = (short)f32_bf16_rne(v0.z); pk[3] = (short)f32_bf16_rne(v0.w);
                pk[4] = (short)f32_bf16_rne(v1.x); pk[5] = (short)f32_bf16_rne(v1.y);
                pk[6] = (short)f32_bf16_rne(v1.z); pk[7] = (short)f32_bf16_rne(v1.w);
                int byte = (r * 128 + c * 2) ^ ((r & 7) << 4);
                *(bf16x8*)((char*)sA + byte) = pk;
            }
        }
        __syncthreads();

#pragma unroll
        for (int ks = 0; ks < 2; ++ks) {
            const int kk = ks * 32 + ((lane >> 4) << 3);
            bf16x8 afr[4], bfr[4];
#pragma unroll
            for (int m = 0; m < 4; ++m) {
                int r = wr * 64 + m * 16 + (lane & 15);
                int byte = (r * 128 + kk * 2) ^ ((r & 7) << 4);
                afr[m] = *(const bf16x8*)((const char*)sA + byte);
            }
#pragma unroll
            for (int n = 0; n < 4; ++n) {
                int r = wc * 64 + n * 16 + (lane & 15);
                int byte = (r * 128 + kk * 2) ^ ((r & 7) << 4);
                bfr[n] = *(const bf16x8*)((const char*)sB + byte);
            }
#pragma unroll
            for (int m = 0; m < 4; ++m)
#pragma unroll
                for (int n = 0; n < 4; ++n)
                    acc[m][n] = __builtin_amdgcn_mfma_f32_16x16x32_bf16(
                        afr[m], bfr[n], acc[m][n], 0, 0, 0);
        }
        __syncthreads();
    }

    const float s = *scale_p;
#pragma unroll
    for (int m = 0; m < 4; ++m)
#pragma unroll
        for (int n = 0; n < 4; ++n) {
            const int col = n0 + wc * 64 + n * 16 + (lane & 15);
            const int rbase = m0 + wr * 64 + m * 16 + ((lane >> 4) << 2);
#pragma unroll
            for (int j = 0; j < 4; ++j)
                C[(size_t)(rbase + j) * N + col] = s * acc[m][n][j];
        }
}

// ---------- last-resort naive path ----------
__global__ void naive_qgemm(const float* __restrict__ X, const float* __restrict__ W,
                            float* __restrict__ out, const float* __restrict__ scale_p,
                            int M) {
    const int col = blockIdx.x * 256 + threadIdx.x;
    const int row = blockIdx.y;
    const float s = *scale_p;
    const float inv = 1.0f / s;
    const float* xr = X + (size_t)row * IN_F;
    const float* wrow = W + (size_t)col * IN_F;
    float acc = 0.f;
    for (int k = 0; k < IN_F; ++k) {
        float q = fminf(fmaxf(rintf(wrow[k] * inv), -2.f), 2.f);
        acc += xr[k] * q;
    }
    out[(size_t)row * OUT_F + col] = acc * s;
}

extern "C" void kernel_launch(void* const* d_in, const int* in_sizes, int n_in,
                              void* d_out, int out_size, void* d_ws, size_t ws_size,
                              hipStream_t stream) {
    const float* x = (const float*)d_in[0];
    const float* W = (const float*)d_in[1];
    float* out = (float*)d_out;
    const int M = in_sizes[0] / IN_F;  // 8192
    const int K = IN_F, N = OUT_F;

    char* ws = (char*)d_ws;
    const size_t OFF_PART = 512;
    const size_t OFF_WQ = OFF_PART + 4096 * sizeof(float);
    const size_t WQ_BYTES = (size_t)N * K * sizeof(ushort);
    const size_t OFF_XH = OFF_WQ + WQ_BYTES;
    const size_t XH_BYTES = (size_t)M * K * sizeof(ushort);
    float* scale = (float*)(ws + 0);
    float* part = (float*)(ws + OFF_PART);
    ushort* wq = (ushort*)(ws + OFF_WQ);
    ushort* xh = (ushort*)(ws + OFF_XH);

    if (ws_size < OFF_WQ) return;

    reduce_abs1<<<4096, 256, 0, stream>>>(W, part);
    reduce_abs2<<<1, 256, 0, stream>>>(part, scale);

    if (ws_size >= OFF_XH + XH_BYTES && (M % 256) == 0 && (N % 256) == 0) {
        quantize_w<<<(N * K / 4) / 256, 256, 0, stream>>>(W, wq, scale);
        cast_x<<<(M * K / 4) / 256, 256, 0, stream>>>(x, xh);
        (void)hipFuncSetAttribute((const void*)qgemm256,
                                  hipFuncAttributeMaxDynamicSharedMemorySize,
                                  131072);
        qgemm256<<<(M / 256) * (N / 256), 512, 131072, stream>>>(
            xh, wq, out, scale, M, N, K);
    } else if (ws_size >= OFF_XH + XH_BYTES) {
        quantize_w<<<(N * K / 4) / 256, 256, 0, stream>>>(W, wq, scale);
        cast_x<<<(M * K / 4) / 256, 256, 0, stream>>>(x, xh);
        qgemm<true><<<(M / 128) * (N / 128), 256, 0, stream>>>(xh, wq, out, scale, M, N, K);
    } else if (ws_size >= OFF_WQ + WQ_BYTES) {
        quantize_w<<<(N * K / 4) / 256, 256, 0, stream>>>(W, wq, scale);
        qgemm<false><<<(M / 128) * (N / 128), 256, 0, stream>>>(x, wq, out, scale, M, N, K);
    } else {
        naive_qgemm<<<dim3(N / 256, M), 256, 0, stream>>>(x, W, out, scale, M);
    }
}

// Round 8
// 313.856 us; speedup vs baseline: 1.0891x; 1.0471x over previous
//
#include <hip/hip_runtime.h>
#include <cstdint>
#include <cstddef>

#define IN_F 4096
#define OUT_F 4096

typedef __attribute__((ext_vector_type(8))) short bf16x8;
typedef __attribute__((ext_vector_type(4))) float f32x4;

__device__ __forceinline__ ushort f32_bf16_rne(float f) {
    uint32_t u = __builtin_bit_cast(uint32_t, f);
    uint32_t r = (u + 0x7FFFu + ((u >> 16) & 1u)) >> 16;
    return (ushort)r;
}

__device__ __forceinline__ void gload_lds16(const void* g, void* l) {
    __builtin_amdgcn_global_load_lds(
        (const __attribute__((address_space(1))) uint32_t*)g,
        (__attribute__((address_space(3))) uint32_t*)l,
        16, 0, 0);
}

__device__ __forceinline__ void bar() {
    asm volatile("s_barrier" ::: "memory");
}

// ---------- deterministic |W| reduction (fixed order, no atomics) ----------
__global__ void reduce_abs1(const float* __restrict__ W, float* __restrict__ part) {
    __shared__ float sm[256];
    const int b = blockIdx.x, t = threadIdx.x;
    const float* p = W + (size_t)b * 4096;
    float s = 0.f;
#pragma unroll
    for (int j = 0; j < 16; ++j) s += fabsf(p[t + 256 * j]);
    sm[t] = s;
    __syncthreads();
    for (int w = 128; w > 0; w >>= 1) {
        if (t < w) sm[t] += sm[t + w];
        __syncthreads();
    }
    if (t == 0) part[b] = sm[0];
}

__global__ void reduce_abs2(const float* __restrict__ part, float* __restrict__ scale) {
    __shared__ float sm[256];
    const int t = threadIdx.x;
    float s = 0.f;
#pragma unroll
    for (int j = 0; j < 16; ++j) s += part[t + 256 * j];
    sm[t] = s;
    __syncthreads();
    for (int w = 128; w > 0; w >>= 1) {
        if (t < w) sm[t] += sm[t + w];
        __syncthreads();
    }
    if (t == 0) {
        float m = sm[0] / 16777216.0f;
        *scale = fmaxf(m, 1e-8f);
    }
}

// ---------- quantize W -> bf16 {-2,-1,0,1,2} (exact in bf16) ----------
__global__ void quantize_w(const float* __restrict__ W, ushort* __restrict__ wq,
                           const float* __restrict__ scale_p) {
    const int i = blockIdx.x * 256 + threadIdx.x;
    const float s = *scale_p;
    float4 v = ((const float4*)W)[i];
    float q0 = fminf(fmaxf(rintf(v.x / s), -2.f), 2.f);
    float q1 = fminf(fmaxf(rintf(v.y / s), -2.f), 2.f);
    float q2 = fminf(fmaxf(rintf(v.z / s), -2.f), 2.f);
    float q3 = fminf(fmaxf(rintf(v.w / s), -2.f), 2.f);
    ushort4 o;
    o.x = f32_bf16_rne(q0); o.y = f32_bf16_rne(q1);
    o.z = f32_bf16_rne(q2); o.w = f32_bf16_rne(q3);
    ((ushort4*)wq)[i] = o;
}

// ---------- cast x -> bf16 (RNE) ----------
__global__ void cast_x(const float* __restrict__ X, ushort* __restrict__ xh) {
    const int i = blockIdx.x * 256 + threadIdx.x;
    float4 v = ((const float4*)X)[i];
    ushort4 o;
    o.x = f32_bf16_rne(v.x); o.y = f32_bf16_rne(v.y);
    o.z = f32_bf16_rne(v.z); o.w = f32_bf16_rne(v.w);
    ((ushort4*)xh)[i] = o;
}

// ========== 256x256 GEMM: 2-barrier K-tile, full-tile register read-ahead =====
// C = scale * (A @ B^T).  A:[M][K] bf16, B:[N][K] bf16 (both K-contiguous).
// 512 threads = 8 waves (2M x 4N); per-wave 128x64 output (acc[8][4], AGPR).
// LDS 128 KiB: 2 K-tile buffers x {A0,A1,B0,B1} 16-KiB halves, XOR-swizzled
// (byte ^= (r&7)<<4) via pre-swizzled global source + swizzled ds_read.
//
// R8 structure (R7 post-mortem: 8 barriers + ~1100 cyc/K-tile of stage-address
// VALU were the residue; schedule micro-order was never the lever):
// per K-tile ONE region, TWO barriers:
//   vmcnt(0)              <- drains {A,B}(kt+1), staged a FULL tile ago: no stall
//   stage {A,B}(kt+2)     <- 8 gload_lds via incrementing pointers (~30 VALU)
//   bar                   <- publishes {A,B}(kt+1)
//   setprio(1)
//   64 MFMA (tile kt, regs read last tile)  ||  24 ds_read (tile kt+1, nxt buf)
//   setprio(0)
//   lgkmcnt(0); bar       <- all reads done before anyone stages over them
// WAR proof: stage(kt+2) overwrites {A,B}(kt) whose reads completed last tile
// (lgkmcnt(0) before that bar). Read-ahead(kt+1) sees data drained by THIS
// tile's vmcnt(0) and published by bar. No counted-vmcnt bookkeeping, no
// same-phase read-after-stage anywhere.
#define BK 64
#define BUF_BYTES 65536

__global__ __launch_bounds__(512, 2) void qgemm256(
        const ushort* __restrict__ Ab, const ushort* __restrict__ Bq,
        float* __restrict__ C, const float* __restrict__ scale_p,
        int M, int N, int K) {
    extern __shared__ __align__(16) char smem[];

    const int t = threadIdx.x;
    const int lane = t & 63;
    const int w = t >> 6;
    const int wr = w >> 2;   // 0..1 (M half)
    const int wc = w & 3;    // 0..3 (N quarter)
    const int bh = wc >> 1;  // B half

    // ---- 2D XCD-aware supertiling (validated R7: FETCH 541->197 MB) ----
    const int MT = M >> 8;
    const int NTiles = N >> 8;
    int mt, nt;
    if (MT == 32 && NTiles == 16 && gridDim.x == 512) {
        const int x = blockIdx.x & 7;
        const int j = blockIdx.x >> 3;
        const int jr = j & 31;
        const int r = j >> 5;
        mt = (x & 3) * 8 + (jr & 7);
        nt = r * 8 + (x >> 2) * 4 + (jr >> 3);
    } else {
        const int nwg = gridDim.x;
        int wg = blockIdx.x;
        if ((nwg & 7) == 0) wg = (wg & 7) * (nwg >> 3) + (wg >> 3);
        mt = wg % MT; nt = wg / MT;
    }
    const int m0 = mt << 8;
    const int n0 = nt << 8;

    const int NT = K / BK;

    // per-lane ds_read byte offsets within a 16-KiB half (add frag*2048)
    int pre[2];
#pragma unroll
    for (int ks = 0; ks < 2; ++ks)
        pre[ks] = (lane & 15) * 128 +
                  (((ks * 64) + ((lane >> 4) * 16)) ^ ((lane & 7) << 4));

    // ---- incrementing stage pointers (swizzled source, linear LDS dest) ----
    const int rowA = t >> 3;                                // 0..63
    const int colsw = ((t & 7) ^ ((t >> 3) & 7)) << 3;      // swizzled col (elems)
    const ushort* gA0 = Ab + (size_t)(m0 + rowA) * K + colsw;
    const ushort* gA1 = Ab + (size_t)(m0 + 128 + rowA) * K + colsw;
    const ushort* gB0 = Bq + (size_t)(n0 + rowA) * K + colsw;
    const ushort* gB1 = Bq + (size_t)(n0 + 128 + rowA) * K + colsw;
    const size_t jrow = (size_t)64 * K;                     // +64 rows (j=1 slice)
    char* lb = smem + t * 16;

    auto stA = [&](uint32_t par) {
        gload_lds16(gA0,        lb + par);
        gload_lds16(gA0 + jrow, lb + par + 8192);
        gload_lds16(gA1,        lb + par + 16384);
        gload_lds16(gA1 + jrow, lb + par + 24576);
        gA0 += 64; gA1 += 64;   // advance one K-tile (128 B)
    };
    auto stB = [&](uint32_t par) {
        gload_lds16(gB0,        lb + par + 32768);
        gload_lds16(gB0 + jrow, lb + par + 40960);
        gload_lds16(gB1,        lb + par + 49152);
        gload_lds16(gB1 + jrow, lb + par + 57344);
        gB0 += 64; gB1 += 64;
    };

    const char* aBbase = smem + wr * 16384;                        // wave's A half
    const char* bBbase = smem + 32768 + bh * 16384 + (wc & 1) * 8192;  // wave's B strip

    f32x4 acc[8][4];
#pragma unroll
    for (int m = 0; m < 8; ++m)
#pragma unroll
        for (int n = 0; n < 4; ++n) acc[m][n] = (f32x4){0.f, 0.f, 0.f, 0.f};

    bf16x8 a0[4][2], a1[4][2], b01[2][2], b23[2][2];

    // ---- prologue: stage tiles 0 (par 0) and 1 (par BUF); preload tile-0 regs
    stA(0); stB(0);
    stA(BUF_BYTES); stB(BUF_BYTES);
    asm volatile("s_waitcnt vmcnt(8)" ::: "memory");   // tile 0 landed
    bar();
#pragma unroll
    for (int m = 0; m < 4; ++m)
#pragma unroll
        for (int ks = 0; ks < 2; ++ks) {
            a0[m][ks] = *(const bf16x8*)(aBbase + m * 2048 + pre[ks]);
            a1[m][ks] = *(const bf16x8*)(aBbase + (m + 4) * 2048 + pre[ks]);
        }
#pragma unroll
    for (int n = 0; n < 2; ++n)
#pragma unroll
        for (int ks = 0; ks < 2; ++ks) {
            b01[n][ks] = *(const bf16x8*)(bBbase + n * 2048 + pre[ks]);
            b23[n][ks] = *(const bf16x8*)(bBbase + (n + 2) * 2048 + pre[ks]);
        }

    for (int kt = 0; kt < NT; ++kt) {
        const uint32_t cur = (uint32_t)(kt & 1) * BUF_BYTES;
        const uint32_t nxt = cur ^ BUF_BYTES;
        const char* aBn = aBbase + nxt;
        const char* bBn = bBbase + nxt;

        // drain {A,B}(kt+1) (issued a full K-tile ago -> no stall)
        asm volatile("s_waitcnt vmcnt(0)" ::: "memory");
        if (kt + 2 < NT) { stA(cur); stB(cur); }   // stage tile kt+2 over tile kt
        bar();                                      // publish tile kt+1

        __builtin_amdgcn_s_setprio(1);
        // ---- 64 MFMA on tile-kt regs (read last tile; no LDS dependency) ----
#pragma unroll
        for (int m = 0; m < 4; ++m)
#pragma unroll
            for (int n = 0; n < 2; ++n)
#pragma unroll
                for (int ks = 0; ks < 2; ++ks)
                    acc[m][n] = __builtin_amdgcn_mfma_f32_16x16x32_bf16(
                        a0[m][ks], b01[n][ks], acc[m][n], 0, 0, 0);
#pragma unroll
        for (int m = 0; m < 4; ++m)
#pragma unroll
            for (int n = 0; n < 2; ++n)
#pragma unroll
                for (int ks = 0; ks < 2; ++ks)
                    acc[m + 4][n] = __builtin_amdgcn_mfma_f32_16x16x32_bf16(
                        a1[m][ks], b01[n][ks], acc[m + 4][n], 0, 0, 0);
#pragma unroll
        for (int m = 0; m < 4; ++m)
#pragma unroll
            for (int n = 0; n < 2; ++n)
#pragma unroll
                for (int ks = 0; ks < 2; ++ks)
                    acc[m][n + 2] = __builtin_amdgcn_mfma_f32_16x16x32_bf16(
                        a0[m][ks], b23[n][ks], acc[m][n + 2], 0, 0, 0);
#pragma unroll
        for (int m = 0; m < 4; ++m)
#pragma unroll
            for (int n = 0; n < 2; ++n)
#pragma unroll
                for (int ks = 0; ks < 2; ++ks)
                    acc[m + 4][n + 2] = __builtin_amdgcn_mfma_f32_16x16x32_bf16(
                        a1[m][ks], b23[n][ks], acc[m + 4][n + 2], 0, 0, 0);
        // ---- full read-ahead of tile kt+1 (independent of the MFMAs above;
        //      compiler renames a0/a1/b01/b23 and interleaves on the DS pipe)
        if (kt + 1 < NT) {
#pragma unroll
            for (int m = 0; m < 4; ++m)
#pragma unroll
                for (int ks = 0; ks < 2; ++ks) {
                    a0[m][ks] = *(const bf16x8*)(aBn + m * 2048 + pre[ks]);
                    a1[m][ks] = *(const bf16x8*)(aBn + (m + 4) * 2048 + pre[ks]);
                }
#pragma unroll
            for (int n = 0; n < 2; ++n)
#pragma unroll
                for (int ks = 0; ks < 2; ++ks) {
                    b01[n][ks] = *(const bf16x8*)(bBn + n * 2048 + pre[ks]);
                    b23[n][ks] = *(const bf16x8*)(bBn + (n + 2) * 2048 + pre[ks]);
                }
        }
        __builtin_amdgcn_s_setprio(0);
        // all LDS reads complete before anyone stages over these regions
        asm volatile("s_waitcnt lgkmcnt(0)" ::: "memory");
        bar();
    }

    const float s = *scale_p;
#pragma unroll
    for (int m = 0; m < 8; ++m)
#pragma unroll
        for (int n = 0; n < 4; ++n) {
            const int col = n0 + wc * 64 + n * 16 + (lane & 15);
            const int rbase = m0 + wr * 128 + m * 16 + ((lane >> 4) << 2);
#pragma unroll
            for (int j = 0; j < 4; ++j)
                C[(size_t)(rbase + j) * N + col] = s * acc[m][n][j];
        }
}

// ---------- 128^2 fallback (validated round 2) ----------
template <bool ABF16>
__global__ __launch_bounds__(256) void qgemm(const void* __restrict__ Aptr,
                                             const ushort* __restrict__ Bq,
                                             float* __restrict__ C,
                                             const float* __restrict__ scale_p,
                                             int M, int N, int K) {
    __shared__ __align__(16) ushort sA[128 * 64];
    __shared__ __align__(16) ushort sB[128 * 64];

    const int t = threadIdx.x;
    const int lane = t & 63;
    const int w = t >> 6;
    const int wr = w >> 1, wc = w & 1;

    const int nwg = gridDim.x;
    int wg = blockIdx.x;
    if ((nwg & 7) == 0) wg = (wg & 7) * (nwg >> 3) + (wg >> 3);
    const int MT = M >> 7;
    const int mt = wg % MT;
    const int nt = wg / MT;
    const int m0 = mt * 128, n0 = nt * 128;

    const ushort* Ab = (const ushort*)Aptr;
    const float* Af = (const float*)Aptr;

    f32x4 zero = {0.f, 0.f, 0.f, 0.f};
    f32x4 acc[4][4];
#pragma unroll
    for (int m = 0; m < 4; ++m)
#pragma unroll
        for (int n = 0; n < 4; ++n) acc[m][n] = zero;

    for (int k0 = 0; k0 < K; k0 += 64) {
#pragma unroll
        for (int i = 0; i < 4; ++i) {
            int e = i * 2048 + t * 8;
            int r = e >> 6, c8 = (e >> 3) & 7;
            int srcc = (c8 ^ (r & 7)) * 8;
            gload_lds16(Bq + (size_t)(n0 + r) * K + (k0 + srcc), &sB[e]);
        }
        if constexpr (ABF16) {
#pragma unroll
            for (int i = 0; i < 4; ++i) {
                int e = i * 2048 + t * 8;
                int r = e >> 6, c8 = (e >> 3) & 7;
                int srcc = (c8 ^ (r & 7)) * 8;
                gload_lds16(Ab + (size_t)(m0 + r) * K + (k0 + srcc), &sA[e]);
            }
        } else {
#pragma unroll
            for (int i = 0; i < 4; ++i) {
                int e = i * 2048 + t * 8;
                int r = e >> 6, c = e & 63;
                const float* src = Af + (size_t)(m0 + r) * K + (k0 + c);
                float4 v0 = *(const float4*)src;
                float4 v1 = *(const float4*)(src + 4);
                bf16x8 pk;
                pk[0] = (short)f32_bf16_rne(v0.x); pk[1] = (short)f32_bf16_rne(v0.y);
                pk[2] = (short)f32_bf16_rne(v0.z); pk[3] = (short)f32_bf16_rne(v0.w);
                pk[4] = (short)f32_bf16_rne(v1.x); pk[5] = (short)f32_bf16_rne(v1.y);
                pk[6] = (short)f32_bf16_rne(v1.z); pk[7] = (short)f32_bf16_rne(v1.w);
                int byte = (r * 128 + c * 2) ^ ((r & 7) << 4);
                *(bf16x8*)((char*)sA + byte) = pk;
            }
        }
        __syncthreads();

#pragma unroll
        for (int ks = 0; ks < 2; ++ks) {
            const int kk = ks * 32 + ((lane >> 4) << 3);
            bf16x8 afr[4], bfr[4];
#pragma unroll
            for (int m = 0; m < 4; ++m) {
                int r = wr * 64 + m * 16 + (lane & 15);
                int byte = (r * 128 + kk * 2) ^ ((r & 7) << 4);
                afr[m] = *(const bf16x8*)((const char*)sA + byte);
            }
#pragma unroll
            for (int n = 0; n < 4; ++n) {
                int r = wc * 64 + n * 16 + (lane & 15);
                int byte = (r * 128 + kk * 2) ^ ((r & 7) << 4);
                bfr[n] = *(const bf16x8*)((const char*)sB + byte);
            }
#pragma unroll
            for (int m = 0; m < 4; ++m)
#pragma unroll
                for (int n = 0; n < 4; ++n)
                    acc[m][n] = __builtin_amdgcn_mfma_f32_16x16x32_bf16(
                        afr[m], bfr[n], acc[m][n], 0, 0, 0);
        }
        __syncthreads();
    }

    const float s = *scale_p;
#pragma unroll
    for (int m = 0; m < 4; ++m)
#pragma unroll
        for (int n = 0; n < 4; ++n) {
            const int col = n0 + wc * 64 + n * 16 + (lane & 15);
            const int rbase = m0 + wr * 64 + m * 16 + ((lane >> 4) << 2);
#pragma unroll
            for (int j = 0; j < 4; ++j)
                C[(size_t)(rbase + j) * N + col] = s * acc[m][n][j];
        }
}

// ---------- last-resort naive path ----------
__global__ void naive_qgemm(const float* __restrict__ X, const float* __restrict__ W,
                            float* __restrict__ out, const float* __restrict__ scale_p,
                            int M) {
    const int col = blockIdx.x * 256 + threadIdx.x;
    const int row = blockIdx.y;
    const float s = *scale_p;
    const float inv = 1.0f / s;
    const float* xr = X + (size_t)row * IN_F;
    const float* wrow = W + (size_t)col * IN_F;
    float acc = 0.f;
    for (int k = 0; k < IN_F; ++k) {
        float q = fminf(fmaxf(rintf(wrow[k] * inv), -2.f), 2.f);
        acc += xr[k] * q;
    }
    out[(size_t)row * OUT_F + col] = acc * s;
}

extern "C" void kernel_launch(void* const* d_in, const int* in_sizes, int n_in,
                              void* d_out, int out_size, void* d_ws, size_t ws_size,
                              hipStream_t stream) {
    const float* x = (const float*)d_in[0];
    const float* W = (const float*)d_in[1];
    float* out = (float*)d_out;
    const int M = in_sizes[0] / IN_F;  // 8192
    const int K = IN_F, N = OUT_F;

    char* ws = (char*)d_ws;
    const size_t OFF_PART = 512;
    const size_t OFF_WQ = OFF_PART + 4096 * sizeof(float);
    const size_t WQ_BYTES = (size_t)N * K * sizeof(ushort);
    const size_t OFF_XH = OFF_WQ + WQ_BYTES;
    const size_t XH_BYTES = (size_t)M * K * sizeof(ushort);
    float* scale = (float*)(ws + 0);
    float* part = (float*)(ws + OFF_PART);
    ushort* wq = (ushort*)(ws + OFF_WQ);
    ushort* xh = (ushort*)(ws + OFF_XH);

    if (ws_size < OFF_WQ) return;

    reduce_abs1<<<4096, 256, 0, stream>>>(W, part);
    reduce_abs2<<<1, 256, 0, stream>>>(part, scale);

    if (ws_size >= OFF_XH + XH_BYTES && (M % 256) == 0 && (N % 256) == 0) {
        quantize_w<<<(N * K / 4) / 256, 256, 0, stream>>>(W, wq, scale);
        cast_x<<<(M * K / 4) / 256, 256, 0, stream>>>(x, xh);
        (void)hipFuncSetAttribute((const void*)qgemm256,
                                  hipFuncAttributeMaxDynamicSharedMemorySize,
                                  131072);
        qgemm256<<<(M / 256) * (N / 256), 512, 131072, stream>>>(
            xh, wq, out, scale, M, N, K);
    } else if (ws_size >= OFF_XH + XH_BYTES) {
        quantize_w<<<(N * K / 4) / 256, 256, 0, stream>>>(W, wq, scale);
        cast_x<<<(M * K / 4) / 256, 256, 0, stream>>>(x, xh);
        qgemm<true><<<(M / 128) * (N / 128), 256, 0, stream>>>(xh, wq, out, scale, M, N, K);
    } else if (ws_size >= OFF_WQ + WQ_BYTES) {
        quantize_w<<<(N * K / 4) / 256, 256, 0, stream>>>(W, wq, scale);
        qgemm<false><<<(M / 128) * (N / 128), 256, 0, stream>>>(x, wq, out, scale, M, N, K);
    } else {
        naive_qgemm<<<dim3(N / 256, M), 256, 0, stream>>>(x, W, out, scale, M);
    }
}

// Round 10
// 313.124 us; speedup vs baseline: 1.0917x; 1.0023x over previous
//
#include <hip/hip_runtime.h>
#include <cstdint>
#include <cstddef>

#define IN_F 4096
#define OUT_F 4096

typedef __attribute__((ext_vector_type(8))) short bf16x8;
typedef __attribute__((ext_vector_type(4))) float f32x4;

__device__ __forceinline__ ushort f32_bf16_rne(float f) {
    uint32_t u = __builtin_bit_cast(uint32_t, f);
    uint32_t r = (u + 0x7FFFu + ((u >> 16) & 1u)) >> 16;
    return (ushort)r;
}

__device__ __forceinline__ void gload_lds16(const void* g, void* l) {
    __builtin_amdgcn_global_load_lds(
        (const __attribute__((address_space(1))) uint32_t*)g,
        (__attribute__((address_space(3))) uint32_t*)l,
        16, 0, 0);
}

__device__ __forceinline__ void bar() {
    asm volatile("s_barrier" ::: "memory");
}

// ---------- deterministic |W| reduction (fixed order, no atomics) ----------
__global__ void reduce_abs1(const float* __restrict__ W, float* __restrict__ part) {
    __shared__ float sm[256];
    const int b = blockIdx.x, t = threadIdx.x;
    const float* p = W + (size_t)b * 4096;
    float s = 0.f;
#pragma unroll
    for (int j = 0; j < 16; ++j) s += fabsf(p[t + 256 * j]);
    sm[t] = s;
    __syncthreads();
    for (int w = 128; w > 0; w >>= 1) {
        if (t < w) sm[t] += sm[t + w];
        __syncthreads();
    }
    if (t == 0) part[b] = sm[0];
}

__global__ void reduce_abs2(const float* __restrict__ part, float* __restrict__ scale) {
    __shared__ float sm[256];
    const int t = threadIdx.x;
    float s = 0.f;
#pragma unroll
    for (int j = 0; j < 16; ++j) s += part[t + 256 * j];
    sm[t] = s;
    __syncthreads();
    for (int w = 128; w > 0; w >>= 1) {
        if (t < w) sm[t] += sm[t + w];
        __syncthreads();
    }
    if (t == 0) {
        float m = sm[0] / 16777216.0f;
        *scale = fmaxf(m, 1e-8f);
    }
}

// ---------- quantize W -> bf16 {-2,-1,0,1,2} (exact in bf16) ----------
__global__ void quantize_w(const float* __restrict__ W, ushort* __restrict__ wq,
                           const float* __restrict__ scale_p) {
    const int i = blockIdx.x * 256 + threadIdx.x;
    const float s = *scale_p;
    float4 v = ((const float4*)W)[i];
    float q0 = fminf(fmaxf(rintf(v.x / s), -2.f), 2.f);
    float q1 = fminf(fmaxf(rintf(v.y / s), -2.f), 2.f);
    float q2 = fminf(fmaxf(rintf(v.z / s), -2.f), 2.f);
    float q3 = fminf(fmaxf(rintf(v.w / s), -2.f), 2.f);
    ushort4 o;
    o.x = f32_bf16_rne(q0); o.y = f32_bf16_rne(q1);
    o.z = f32_bf16_rne(q2); o.w = f32_bf16_rne(q3);
    ((ushort4*)wq)[i] = o;
}

// ---------- cast x -> bf16 (RNE) ----------
__global__ void cast_x(const float* __restrict__ X, ushort* __restrict__ xh) {
    const int i = blockIdx.x * 256 + threadIdx.x;
    float4 v = ((const float4*)X)[i];
    ushort4 o;
    o.x = f32_bf16_rne(v.x); o.y = f32_bf16_rne(v.y);
    o.z = f32_bf16_rne(v.z); o.w = f32_bf16_rne(v.w);
    ((ushort4*)xh)[i] = o;
}

// ======= 256x256 GEMM: same-tile interleaved read+MFMA (R10) ===============
// C = scale * (A @ B^T).  A:[M][K] bf16, B:[N][K] bf16 (both K-contiguous).
// 512 threads = 8 waves (2M x 4N); per-wave 128x64 output (acc[8][4], AGPR).
// LDS 128 KiB: 2 K-tile buffers x {A0,A1,B0,B1} 16-KiB halves, XOR-swizzled
// (byte ^= (r&7)<<4) via pre-swizzled global source + swizzled ds_read.
//
// R10 insight (R8 post-mortem): read-AHEAD of the next tile cannot overlap
// the MFMA cluster -- it overwrites af/bf in place, and duplicating frags
// (96 VGPR) on top of acc (128) exceeds the register file, so the compiler
// serializes reads AFTER the MFMAs: 2483 (MFMA) + 2304 (LDS) ~= 4900 cyc
// observed.  Fix: read the CURRENT tile's frags in the same region as their
// consuming MFMAs -- the compiler emits fine-grained lgkmcnt(N) (m97 asm),
// so MFMA block m executes while reads for m+1 are in flight; LDS pipe hides
// under MFMA pipe with no register duplication.
//
// Per K-tile: { stage(kt+1 -> other buf); vmcnt(8) [stage(kt) drained, the
// 8 just-issued stay in flight]; bar [publish tile kt]; setprio1; 24 ds_read
// + 64 MFMA interleaved; setprio0; lgkmcnt(0); bar }.
// WAR: stage(kt+1) overwrites tile kt-1, whose reads were lgkm-drained
// before kt-1's end-bar (one full barrier earlier).  Tail: last tile has no
// stage -> vmcnt(0).
#define BK 64
#define BUF_BYTES 65536

__global__ __launch_bounds__(512, 2) void qgemm256(
        const ushort* __restrict__ Ab, const ushort* __restrict__ Bq,
        float* __restrict__ C, const float* __restrict__ scale_p,
        int M, int N, int K) {
    extern __shared__ __align__(16) char smem[];

    const int t = threadIdx.x;
    const int lane = t & 63;
    const int w = t >> 6;
    const int wr = w >> 2;   // 0..1 (M half)
    const int wc = w & 3;    // 0..3 (N quarter)
    const int bh = wc >> 1;  // B half

    // ---- 2D XCD-aware supertiling (validated R7: FETCH 541->197 MB) ----
    const int MT = M >> 8;
    const int NTiles = N >> 8;
    int mt, nt;
    if (MT == 32 && NTiles == 16 && gridDim.x == 512) {
        const int x = blockIdx.x & 7;
        const int j = blockIdx.x >> 3;
        const int jr = j & 31;
        const int r = j >> 5;
        mt = (x & 3) * 8 + (jr & 7);
        nt = r * 8 + (x >> 2) * 4 + (jr >> 3);
    } else {
        const int nwg = gridDim.x;
        int wg = blockIdx.x;
        if ((nwg & 7) == 0) wg = (wg & 7) * (nwg >> 3) + (wg >> 3);
        mt = wg % MT; nt = wg / MT;
    }
    const int m0 = mt << 8;
    const int n0 = nt << 8;

    const int NT = K / BK;

    // per-lane ds_read byte offsets within a 16-KiB half (add frag*2048)
    int pre[2];
#pragma unroll
    for (int ks = 0; ks < 2; ++ks)
        pre[ks] = (lane & 15) * 128 +
                  (((ks * 64) + ((lane >> 4) * 16)) ^ ((lane & 7) << 4));

    // ---- incrementing stage pointers (swizzled source, linear LDS dest) ----
    const int rowA = t >> 3;                                // 0..63
    const int colsw = ((t & 7) ^ ((t >> 3) & 7)) << 3;      // swizzled col (elems)
    const ushort* gA0 = Ab + (size_t)(m0 + rowA) * K + colsw;
    const ushort* gA1 = Ab + (size_t)(m0 + 128 + rowA) * K + colsw;
    const ushort* gB0 = Bq + (size_t)(n0 + rowA) * K + colsw;
    const ushort* gB1 = Bq + (size_t)(n0 + 128 + rowA) * K + colsw;
    const size_t jrow = (size_t)64 * K;                     // +64 rows (j=1 slice)
    char* lb = smem + t * 16;

    auto stA = [&](uint32_t par) {
        gload_lds16(gA0,        lb + par);
        gload_lds16(gA0 + jrow, lb + par + 8192);
        gload_lds16(gA1,        lb + par + 16384);
        gload_lds16(gA1 + jrow, lb + par + 24576);
        gA0 += 64; gA1 += 64;   // advance one K-tile (128 B)
    };
    auto stB = [&](uint32_t par) {
        gload_lds16(gB0,        lb + par + 32768);
        gload_lds16(gB0 + jrow, lb + par + 40960);
        gload_lds16(gB1,        lb + par + 49152);
        gload_lds16(gB1 + jrow, lb + par + 57344);
        gB0 += 64; gB1 += 64;
    };

    const char* aBbase = smem + wr * 16384;                        // wave's A half
    const char* bBbase = smem + 32768 + bh * 16384 + (wc & 1) * 8192;  // wave's B strip

    f32x4 acc[8][4];
#pragma unroll
    for (int m = 0; m < 8; ++m)
#pragma unroll
        for (int n = 0; n < 4; ++n) acc[m][n] = (f32x4){0.f, 0.f, 0.f, 0.f};

    // ---- prologue: stage tile 0 into buffer 0 ----
    stA(0); stB(0);

    for (int kt = 0; kt < NT; ++kt) {
        const uint32_t cur = (uint32_t)(kt & 1) * BUF_BYTES;
        const char* aB = aBbase + cur;
        const char* bB = bBbase + cur;

        // stage tile kt+1 into the other buffer (held tile kt-1; its reads
        // were lgkm-drained before kt-1's end-bar), then wait for stage(kt).
        if (kt + 1 < NT) {
            stA(cur ^ BUF_BYTES); stB(cur ^ BUF_BYTES);
            asm volatile("s_waitcnt vmcnt(8)" ::: "memory");  // stage(kt) done
        } else {
            asm volatile("s_waitcnt vmcnt(0)" ::: "memory");  // tail drain
        }
        bar();  // publish tile kt

        __builtin_amdgcn_s_setprio(1);
        // ---- same-region reads + MFMAs: compiler pipelines with fine lgkm ----
        bf16x8 a0[4][2], a1[4][2], b01[2][2], b23[2][2];
#pragma unroll
        for (int n = 0; n < 2; ++n)
#pragma unroll
            for (int ks = 0; ks < 2; ++ks) {
                b01[n][ks] = *(const bf16x8*)(bB + n * 2048 + pre[ks]);
                b23[n][ks] = *(const bf16x8*)(bB + (n + 2) * 2048 + pre[ks]);
            }
#pragma unroll
        for (int m = 0; m < 4; ++m)
#pragma unroll
            for (int ks = 0; ks < 2; ++ks) {
                a0[m][ks] = *(const bf16x8*)(aB + m * 2048 + pre[ks]);
                a1[m][ks] = *(const bf16x8*)(aB + (m + 4) * 2048 + pre[ks]);
            }
#pragma unroll
        for (int m = 0; m < 4; ++m)
#pragma unroll
            for (int n = 0; n < 2; ++n)
#pragma unroll
                for (int ks = 0; ks < 2; ++ks)
                    acc[m][n] = __builtin_amdgcn_mfma_f32_16x16x32_bf16(
                        a0[m][ks], b01[n][ks], acc[m][n], 0, 0, 0);
#pragma unroll
        for (int m = 0; m < 4; ++m)
#pragma unroll
            for (int n = 0; n < 2; ++n)
#pragma unroll
                for (int ks = 0; ks < 2; ++ks)
                    acc[m + 4][n] = __builtin_amdgcn_mfma_f32_16x16x32_bf16(
                        a1[m][ks], b01[n][ks], acc[m + 4][n], 0, 0, 0);
#pragma unroll
        for (int m = 0; m < 4; ++m)
#pragma unroll
            for (int n = 0; n < 2; ++n)
#pragma unroll
                for (int ks = 0; ks < 2; ++ks)
                    acc[m][n + 2] = __builtin_amdgcn_mfma_f32_16x16x32_bf16(
                        a0[m][ks], b23[n][ks], acc[m][n + 2], 0, 0, 0);
#pragma unroll
        for (int m = 0; m < 4; ++m)
#pragma unroll
            for (int n = 0; n < 2; ++n)
#pragma unroll
                for (int ks = 0; ks < 2; ++ks)
                    acc[m + 4][n + 2] = __builtin_amdgcn_mfma_f32_16x16x32_bf16(
                        a1[m][ks], b23[n][ks], acc[m + 4][n + 2], 0, 0, 0);
        __builtin_amdgcn_s_setprio(0);
        // all LDS reads complete before anyone stages over this buffer
        asm volatile("s_waitcnt lgkmcnt(0)" ::: "memory");
        bar();
    }

    const float s = *scale_p;
#pragma unroll
    for (int m = 0; m < 8; ++m)
#pragma unroll
        for (int n = 0; n < 4; ++n) {
            const int col = n0 + wc * 64 + n * 16 + (lane & 15);
            const int rbase = m0 + wr * 128 + m * 16 + ((lane >> 4) << 2);
#pragma unroll
            for (int j = 0; j < 4; ++j)
                C[(size_t)(rbase + j) * N + col] = s * acc[m][n][j];
        }
}

// ---------- 128^2 fallback (validated round 2) ----------
template <bool ABF16>
__global__ __launch_bounds__(256) void qgemm(const void* __restrict__ Aptr,
                                             const ushort* __restrict__ Bq,
                                             float* __restrict__ C,
                                             const float* __restrict__ scale_p,
                                             int M, int N, int K) {
    __shared__ __align__(16) ushort sA[128 * 64];
    __shared__ __align__(16) ushort sB[128 * 64];

    const int t = threadIdx.x;
    const int lane = t & 63;
    const int w = t >> 6;
    const int wr = w >> 1, wc = w & 1;

    const int nwg = gridDim.x;
    int wg = blockIdx.x;
    if ((nwg & 7) == 0) wg = (wg & 7) * (nwg >> 3) + (wg >> 3);
    const int MT = M >> 7;
    const int mt = wg % MT;
    const int nt = wg / MT;
    const int m0 = mt * 128, n0 = nt * 128;

    const ushort* Ab = (const ushort*)Aptr;
    const float* Af = (const float*)Aptr;

    f32x4 zero = {0.f, 0.f, 0.f, 0.f};
    f32x4 acc[4][4];
#pragma unroll
    for (int m = 0; m < 4; ++m)
#pragma unroll
        for (int n = 0; n < 4; ++n) acc[m][n] = zero;

    for (int k0 = 0; k0 < K; k0 += 64) {
#pragma unroll
        for (int i = 0; i < 4; ++i) {
            int e = i * 2048 + t * 8;
            int r = e >> 6, c8 = (e >> 3) & 7;
            int srcc = (c8 ^ (r & 7)) * 8;
            gload_lds16(Bq + (size_t)(n0 + r) * K + (k0 + srcc), &sB[e]);
        }
        if constexpr (ABF16) {
#pragma unroll
            for (int i = 0; i < 4; ++i) {
                int e = i * 2048 + t * 8;
                int r = e >> 6, c8 = (e >> 3) & 7;
                int srcc = (c8 ^ (r & 7)) * 8;
                gload_lds16(Ab + (size_t)(m0 + r) * K + (k0 + srcc), &sA[e]);
            }
        } else {
#pragma unroll
            for (int i = 0; i < 4; ++i) {
                int e = i * 2048 + t * 8;
                int r = e >> 6, c = e & 63;
                const float* src = Af + (size_t)(m0 + r) * K + (k0 + c);
                float4 v0 = *(const float4*)src;
                float4 v1 = *(const float4*)(src + 4);
                bf16x8 pk;
                pk[0] = (short)f32_bf16_rne(v0.x); pk[1] = (short)f32_bf16_rne(v0.y);
                pk[2] = (short)f32_bf16_rne(v0.z); pk[3] = (short)f32_bf16_rne(v0.w);
                pk[4] = (short)f32_bf16_rne(v1.x); pk[5] = (short)f32_bf16_rne(v1.y);
                pk[6] = (short)f32_bf16_rne(v1.z); pk[7] = (short)f32_bf16_rne(v1.w);
                int byte = (r * 128 + c * 2) ^ ((r & 7) << 4);
                *(bf16x8*)((char*)sA + byte) = pk;
            }
        }
        __syncthreads();

#pragma unroll
        for (int ks = 0; ks < 2; ++ks) {
            const int kk = ks * 32 + ((lane >> 4) << 3);
            bf16x8 afr[4], bfr[4];
#pragma unroll
            for (int m = 0; m < 4; ++m) {
                int r = wr * 64 + m * 16 + (lane & 15);
                int byte = (r * 128 + kk * 2) ^ ((r & 7) << 4);
                afr[m] = *(const bf16x8*)((const char*)sA + byte);
            }
#pragma unroll
            for (int n = 0; n < 4; ++n) {
                int r = wc * 64 + n * 16 + (lane & 15);
                int byte = (r * 128 + kk * 2) ^ ((r & 7) << 4);
                bfr[n] = *(const bf16x8*)((const char*)sB + byte);
            }
#pragma unroll
            for (int m = 0; m < 4; ++m)
#pragma unroll
                for (int n = 0; n < 4; ++n)
                    acc[m][n] = __builtin_amdgcn_mfma_f32_16x16x32_bf16(
                        afr[m], bfr[n], acc[m][n], 0, 0, 0);
        }
        __syncthreads();
    }

    const float s = *scale_p;
#pragma unroll
    for (int m = 0; m < 4; ++m)
#pragma unroll
        for (int n = 0; n < 4; ++n) {
            const int col = n0 + wc * 64 + n * 16 + (lane & 15);
            const int rbase = m0 + wr * 64 + m * 16 + ((lane >> 4) << 2);
#pragma unroll
            for (int j = 0; j < 4; ++j)
                C[(size_t)(rbase + j) * N + col] = s * acc[m][n][j];
        }
}

// ---------- last-resort naive path ----------
__global__ void naive_qgemm(const float* __restrict__ X, const float* __restrict__ W,
                            float* __restrict__ out, const float* __restrict__ scale_p,
                            int M) {
    const int col = blockIdx.x * 256 + threadIdx.x;
    const int row = blockIdx.y;
    const float s = *scale_p;
    const float inv = 1.0f / s;
    const float* xr = X + (size_t)row * IN_F;
    const float* wrow = W + (size_t)col * IN_F;
    float acc = 0.f;
    for (int k = 0; k < IN_F; ++k) {
        float q = fminf(fmaxf(rintf(wrow[k] * inv), -2.f), 2.f);
        acc += xr[k] * q;
    }
    out[(size_t)row * OUT_F + col] = acc * s;
}

extern "C" void kernel_launch(void* const* d_in, const int* in_sizes, int n_in,
                              void* d_out, int out_size, void* d_ws, size_t ws_size,
                              hipStream_t stream) {
    const float* x = (const float*)d_in[0];
    const float* W = (const float*)d_in[1];
    float* out = (float*)d_out;
    const int M = in_sizes[0] / IN_F;  // 8192
    const int K = IN_F, N = OUT_F;

    char* ws = (char*)d_ws;
    const size_t OFF_PART = 512;
    const size_t OFF_WQ = OFF_PART + 4096 * sizeof(float);
    const size_t WQ_BYTES = (size_t)N * K * sizeof(ushort);
    const size_t OFF_XH = OFF_WQ + WQ_BYTES;
    const size_t XH_BYTES = (size_t)M * K * sizeof(ushort);
    float* scale = (float*)(ws + 0);
    float* part = (float*)(ws + OFF_PART);
    ushort* wq = (ushort*)(ws + OFF_WQ);
    ushort* xh = (ushort*)(ws + OFF_XH);

    if (ws_size < OFF_WQ) return;

    reduce_abs1<<<4096, 256, 0, stream>>>(W, part);
    reduce_abs2<<<1, 256, 0, stream>>>(part, scale);

    if (ws_size >= OFF_XH + XH_BYTES && (M % 256) == 0 && (N % 256) == 0) {
        quantize_w<<<(N * K / 4) / 256, 256, 0, stream>>>(W, wq, scale);
        cast_x<<<(M * K / 4) / 256, 256, 0, stream>>>(x, xh);
        (void)hipFuncSetAttribute((const void*)qgemm256,
                                  hipFuncAttributeMaxDynamicSharedMemorySize,
                                  131072);
        qgemm256<<<(M / 256) * (N / 256), 512, 131072, stream>>>(
            xh, wq, out, scale, M, N, K);
    } else if (ws_size >= OFF_XH + XH_BYTES) {
        quantize_w<<<(N * K / 4) / 256, 256, 0, stream>>>(W, wq, scale);
        cast_x<<<(M * K / 4) / 256, 256, 0, stream>>>(x, xh);
        qgemm<true><<<(M / 128) * (N / 128), 256, 0, stream>>>(xh, wq, out, scale, M, N, K);
    } else if (ws_size >= OFF_WQ + WQ_BYTES) {
        quantize_w<<<(N * K / 4) / 256, 256, 0, stream>>>(W, wq, scale);
        qgemm<false><<<(M / 128) * (N / 128), 256, 0, stream>>>(x, wq, out, scale, M, N, K);
    } else {
        naive_qgemm<<<dim3(N / 256, M), 256, 0, stream>>>(x, W, out, scale, M);
    }
}